// Round 2
// baseline (1615.625 us; speedup 1.0000x reference)
//
#include <hip/hip_runtime.h>
#include <hip/hip_bf16.h>
#include <cstdint>
#include <cstddef>

#define NGENE 100000
#define NDIS  20000
#define FDIM  128
#define HIDD  128
#define OUTF  64
#define EGG   400000
#define EGD   100000
#define EDG   100000
#define ETOT  (EGG + EGD + EDG)
#define NSLOT (NGENE + NDIS + NGENE)   // g2g slots [0,NG) | g2d [NG,NG+ND) | d2g [NG+ND,...)
#define SLOPE 0.2f

static __device__ __forceinline__ float leaky(float x) { return x > 0.f ? x : SLOPE * x; }

// ---------------------------------------------------------------- GEMM [N,128]@[128,NCOL]
template<int NCOL, bool BIAS>
__global__ __launch_bounds__(256) void gemm_k128(const float* __restrict__ X,
                                                 const float* __restrict__ W,
                                                 const float* __restrict__ bias,
                                                 float* __restrict__ H, int N)
{
    constexpr int NTC = NCOL / 4;      // float4 col-groups
    constexpr int NTR = 256 / NTC;     // distinct ty values
    constexpr int RPT = 64 / NTR;      // rows per thread
    __shared__ float xs[64][128];
    const int r0  = blockIdx.x * 64;
    const int tid = threadIdx.x;
    for (int i = tid; i < 64 * 32; i += 256) {
        int r = i >> 5, c4 = i & 31;
        float4 v = make_float4(0.f, 0.f, 0.f, 0.f);
        if (r0 + r < N) v = ((const float4*)X)[(size_t)(r0 + r) * 32 + c4];
        ((float4*)xs[r])[c4] = v;
    }
    __syncthreads();
    const int tx = tid % NTC, ty = tid / NTC;
    float4 b4 = make_float4(0.f, 0.f, 0.f, 0.f);
    if (BIAS) b4 = ((const float4*)bias)[tx];
    const float4* W4 = (const float4*)W;
    for (int rr = 0; rr < RPT; ++rr) {
        int r = rr * NTR + ty;
        float ax = 0.f, ay = 0.f, az = 0.f, aw = 0.f;
        #pragma unroll 4
        for (int k = 0; k < 128; k += 4) {
            float4 xv = *(const float4*)&xs[r][k];
            float4 w0 = W4[(k + 0) * NTC + tx];
            float4 w1 = W4[(k + 1) * NTC + tx];
            float4 w2 = W4[(k + 2) * NTC + tx];
            float4 w3 = W4[(k + 3) * NTC + tx];
            ax += xv.x * w0.x + xv.y * w1.x + xv.z * w2.x + xv.w * w3.x;
            ay += xv.x * w0.y + xv.y * w1.y + xv.z * w2.y + xv.w * w3.y;
            az += xv.x * w0.z + xv.y * w1.z + xv.z * w2.z + xv.w * w3.z;
            aw += xv.x * w0.w + xv.y * w1.w + xv.z * w2.w + xv.w * w3.w;
        }
        if (r0 + r < N) {
            float4 o = make_float4(ax + b4.x, ay + b4.y, az + b4.z, aw + b4.w);
            ((float4*)H)[(size_t)(r0 + r) * NTC + tx] = o;
        }
    }
}

// ---------------------------------------------------------------- attention vectors: av[mat][f] = sum_h W[t][f][h]*a[t][h]
__global__ __launch_bounds__(64) void compute_av(const float* __restrict__ Ws1, const float* __restrict__ Wd1,
                                                 const float* __restrict__ as1, const float* __restrict__ ad1,
                                                 const float* __restrict__ Ws2, const float* __restrict__ Wd2,
                                                 const float* __restrict__ as2, const float* __restrict__ ad2,
                                                 float* __restrict__ av)
{
    int b = blockIdx.x;              // 0..1535
    int mat = b >> 7, f = b & 127;   // mat: [layer][6] ; 6 = vs0,vs1,vs2,vd0,vd1,vd2
    int layer = mat / 6, idx = mat % 6;
    int t = (idx < 3) ? idx : idx - 3;
    const float* W; const float* a;
    if (layer == 0) { W = (idx < 3) ? Ws1 : Wd1; a = (idx < 3) ? as1 : ad1; }
    else           { W = (idx < 3) ? Ws2 : Wd2; a = (idx < 3) ? as2 : ad2; }
    const float* Wrow = W + ((size_t)t * 128 + f) * 128;
    const float* avec = a + t * 128;
    int lane = threadIdx.x;
    float2 w  = ((const float2*)Wrow)[lane];
    float2 aa = ((const float2*)avec)[lane];
    float d = w.x * aa.x + w.y * aa.y;
    for (int off = 32; off; off >>= 1) d += __shfl_down(d, off);
    if (lane == 0) av[mat * 128 + f] = d;
}

// ---------------------------------------------------------------- per-node scalar dots
__global__ __launch_bounds__(256) void node_dots_gene(const float* __restrict__ X, const float* __restrict__ av,
                                                      float* __restrict__ es0, float* __restrict__ es1,
                                                      float* __restrict__ ed0, float* __restrict__ ed2, int N)
{
    int n = blockIdx.x * 4 + (threadIdx.x >> 6);
    if (n >= N) return;
    int lane = threadIdx.x & 63;
    float2 x  = ((const float2*)(X + (size_t)n * 128))[lane];
    float2 a0 = ((const float2*)(av + 0 * 128))[lane];
    float2 a1 = ((const float2*)(av + 1 * 128))[lane];
    float2 a3 = ((const float2*)(av + 3 * 128))[lane];
    float2 a5 = ((const float2*)(av + 5 * 128))[lane];
    float d0 = x.x * a0.x + x.y * a0.y;
    float d1 = x.x * a1.x + x.y * a1.y;
    float d3 = x.x * a3.x + x.y * a3.y;
    float d5 = x.x * a5.x + x.y * a5.y;
    for (int off = 32; off; off >>= 1) {
        d0 += __shfl_down(d0, off);
        d1 += __shfl_down(d1, off);
        d3 += __shfl_down(d3, off);
        d5 += __shfl_down(d5, off);
    }
    if (lane == 0) { es0[n] = d0; es1[n] = d1; ed0[n] = d3; ed2[n] = d5; }
}

__global__ __launch_bounds__(256) void node_dots_dis(const float* __restrict__ X, const float* __restrict__ av,
                                                     float* __restrict__ es2, float* __restrict__ ed1, int N)
{
    int n = blockIdx.x * 4 + (threadIdx.x >> 6);
    if (n >= N) return;
    int lane = threadIdx.x & 63;
    float2 x  = ((const float2*)(X + (size_t)n * 128))[lane];
    float2 a2 = ((const float2*)(av + 2 * 128))[lane];
    float2 a4 = ((const float2*)(av + 4 * 128))[lane];
    float d2 = x.x * a2.x + x.y * a2.y;
    float d4 = x.x * a4.x + x.y * a4.y;
    for (int off = 32; off; off >>= 1) {
        d2 += __shfl_down(d2, off);
        d4 += __shfl_down(d4, off);
    }
    if (lane == 0) { es2[n] = d2; ed1[n] = d4; }
}

// ---------------------------------------------------------------- CSR build
__global__ void hist_edges(const int* __restrict__ gg_d, const int* __restrict__ gd_d,
                           const int* __restrict__ dg_d, int* __restrict__ counts)
{
    int i = blockIdx.x * blockDim.x + threadIdx.x;
    if (i >= ETOT) return;
    int slot;
    if (i < EGG) slot = gg_d[i];
    else if (i < EGG + EGD) slot = NGENE + gd_d[i - EGG];
    else slot = NGENE + NDIS + dg_d[i - EGG - EGD];
    atomicAdd(&counts[slot], 1);
}

__global__ __launch_bounds__(256) void scan_blocks(const int* __restrict__ counts, int* __restrict__ rowptr,
                                                   int* __restrict__ partials, int n)
{
    __shared__ int sdata[256];
    int base = blockIdx.x * 2048;
    int tid  = threadIdx.x;
    int local[8]; int s = 0;
    #pragma unroll
    for (int j = 0; j < 8; ++j) {
        int idx = base + tid * 8 + j;
        int v = (idx < n) ? counts[idx] : 0;
        local[j] = s; s += v;
    }
    sdata[tid] = s;
    __syncthreads();
    for (int off = 1; off < 256; off <<= 1) {
        int v = 0;
        if (tid >= off) v = sdata[tid - off];
        __syncthreads();
        if (tid >= off) sdata[tid] += v;
        __syncthreads();
    }
    int texcl = (tid ? sdata[tid - 1] : 0);
    #pragma unroll
    for (int j = 0; j < 8; ++j) {
        int idx = base + tid * 8 + j;
        if (idx < n) rowptr[idx] = local[j] + texcl;
    }
    if (tid == 255) partials[blockIdx.x] = sdata[255];
}

__global__ __launch_bounds__(256) void scan_partials(int* __restrict__ partials, int nb)
{
    __shared__ int sdata[256];
    int tid = threadIdx.x;
    sdata[tid] = (tid < nb) ? partials[tid] : 0;
    __syncthreads();
    for (int off = 1; off < 256; off <<= 1) {
        int v = 0;
        if (tid >= off) v = sdata[tid - off];
        __syncthreads();
        if (tid >= off) sdata[tid] += v;
        __syncthreads();
    }
    partials[tid] = (tid ? sdata[tid - 1] : 0);
}

__global__ void scan_add(int* __restrict__ rowptr, const int* __restrict__ partials, int n)
{
    int i = blockIdx.x * blockDim.x + threadIdx.x;
    if (i < n) rowptr[i] += partials[i >> 11];
    if (i == 0) rowptr[n] = ETOT;
}

__global__ void scatter_edges(const int* __restrict__ gg_s, const int* __restrict__ gg_d,
                              const int* __restrict__ gd_s, const int* __restrict__ gd_d,
                              const int* __restrict__ dg_s, const int* __restrict__ dg_d,
                              const int* __restrict__ rowptr, int* __restrict__ cursor, int* __restrict__ col)
{
    int i = blockIdx.x * blockDim.x + threadIdx.x;
    if (i >= ETOT) return;
    int slot, src;
    if (i < EGG) { slot = gg_d[i]; src = gg_s[i]; }
    else if (i < EGG + EGD) { int j = i - EGG; slot = NGENE + gd_d[j]; src = gd_s[j]; }
    else { int j = i - EGG - EGD; slot = NGENE + NDIS + dg_d[j]; src = dg_s[j]; }
    int pos = atomicAdd(&cursor[slot], 1);
    col[rowptr[slot] + pos] = src;
}

// ---------------------------------------------------------------- softmax-aggregate (wave per dst node)
__device__ __forceinline__ void seg_accum(const int* __restrict__ rowptr, const int* __restrict__ col,
                                          int slot, const float* __restrict__ hs,
                                          const float* __restrict__ es, float edv,
                                          int lane, float& ax, float& ay)
{
    int s = rowptr[slot], e = rowptr[slot + 1];
    if (e <= s) return;
    float m = -1e30f;
    for (int i = s; i < e; ++i) m = fmaxf(m, leaky(es[col[i]] + edv));
    float denom = 0.f; float sx = 0.f, sy = 0.f;
    for (int i = s; i < e; ++i) {
        int sn = col[i];
        float p = __expf(leaky(es[sn] + edv) - m);
        denom += p;
        float2 hv = ((const float2*)(hs + (size_t)sn * HIDD))[lane];
        sx += p * hv.x; sy += p * hv.y;
    }
    float inv = 1.0f / denom;
    ax += sx * inv; ay += sy * inv;
}

template<bool TWO>
__global__ __launch_bounds__(256) void agg_gat(const int* __restrict__ rowptr, const int* __restrict__ col,
    int baseA, const float* __restrict__ hsA, const float* __restrict__ esA, const float* __restrict__ edA,
    const float* __restrict__ biasA,
    int baseB, const float* __restrict__ hsB, const float* __restrict__ esB, const float* __restrict__ edB,
    const float* __restrict__ biasB,
    float* __restrict__ out, int N)
{
    int wid = blockIdx.x * 4 + (threadIdx.x >> 6);
    if (wid >= N) return;
    int lane = threadIdx.x & 63;
    float ax = 0.f, ay = 0.f;
    seg_accum(rowptr, col, baseA + wid, hsA, esA, edA[wid], lane, ax, ay);
    if (TWO) seg_accum(rowptr, col, baseB + wid, hsB, esB, edB[wid], lane, ax, ay);
    int c = lane * 2;
    float bx = biasA[c]     + (TWO ? biasB[c]     : 0.f);
    float by = biasA[c + 1] + (TWO ? biasB[c + 1] : 0.f);
    ((float2*)(out + (size_t)wid * HIDD))[lane] =
        make_float2(fmaxf(ax + bx, 0.f), fmaxf(ay + by, 0.f));
}

// ---------------------------------------------------------------- launch
extern "C" void kernel_launch(void* const* d_in, const int* in_sizes, int n_in,
                              void* d_out, int out_size, void* d_ws, size_t ws_size,
                              hipStream_t stream)
{
    const float* xg  = (const float*)d_in[0];
    const float* xd  = (const float*)d_in[1];
    const float* Ws1 = (const float*)d_in[2];
    const float* Wd1 = (const float*)d_in[3];
    const float* as1 = (const float*)d_in[4];
    const float* ad1 = (const float*)d_in[5];
    const float* b1  = (const float*)d_in[6];
    const float* Ws2 = (const float*)d_in[7];
    const float* Wd2 = (const float*)d_in[8];
    const float* as2 = (const float*)d_in[9];
    const float* ad2 = (const float*)d_in[10];
    const float* b2  = (const float*)d_in[11];
    const float* Wg  = (const float*)d_in[12];
    const float* bg  = (const float*)d_in[13];
    const float* Wdh = (const float*)d_in[14];
    const float* bd  = (const float*)d_in[15];
    const int* gg_s = (const int*)d_in[16];
    const int* gg_d = (const int*)d_in[17];
    const int* gd_s = (const int*)d_in[18];
    const int* gd_d = (const int*)d_in[19];
    const int* dg_s = (const int*)d_in[20];
    const int* dg_d = (const int*)d_in[21];
    float* out = (float*)d_out;

    size_t p = 0;
    char* ws = (char*)d_ws;
    auto alloc_f = [&](size_t n) { float* r = (float*)(ws + p); p += n * sizeof(float); return r; };
    auto alloc_i = [&](size_t n) { int*   r = (int*)(ws + p);   p += n * sizeof(int);   return r; };

    float* hs0 = alloc_f((size_t)NGENE * HIDD);
    float* hs1 = alloc_f((size_t)NGENE * HIDD);
    float* hs2 = alloc_f((size_t)NDIS  * HIDD);
    float* h1g = alloc_f((size_t)NGENE * HIDD);
    float* h1d = alloc_f((size_t)NDIS  * HIDD);
    float* av  = alloc_f(12 * 128);
    float* es0 = alloc_f(NGENE);
    float* es1 = alloc_f(NGENE);
    float* ed0 = alloc_f(NGENE);
    float* ed2 = alloc_f(NGENE);
    float* es2 = alloc_f(NDIS);
    float* ed1 = alloc_f(NDIS);
    int* counts   = alloc_i(NSLOT);
    int* rowptr   = alloc_i(NSLOT + 1);
    int* partials = alloc_i(256);
    int* col      = alloc_i(ETOT);
    (void)ws_size; (void)in_sizes; (void)n_in; (void)out_size;

    const int SCAN_BLOCKS = (NSLOT + 2047) / 2048;   // 108

    // ---- CSR build (shared by both layers)
    hipMemsetAsync(counts, 0, (size_t)NSLOT * sizeof(int), stream);
    hist_edges<<<(ETOT + 255) / 256, 256, 0, stream>>>(gg_d, gd_d, dg_d, counts);
    scan_blocks<<<SCAN_BLOCKS, 256, 0, stream>>>(counts, rowptr, partials, NSLOT);
    scan_partials<<<1, 256, 0, stream>>>(partials, SCAN_BLOCKS);
    scan_add<<<(NSLOT + 255) / 256, 256, 0, stream>>>(rowptr, partials, NSLOT);
    hipMemsetAsync(counts, 0, (size_t)NSLOT * sizeof(int), stream);
    scatter_edges<<<(ETOT + 255) / 256, 256, 0, stream>>>(gg_s, gg_d, gd_s, gd_d, dg_s, dg_d,
                                                          rowptr, counts, col);

    // ---- attention vectors for both layers
    compute_av<<<1536, 64, 0, stream>>>(Ws1, Wd1, as1, ad1, Ws2, Wd2, as2, ad2, av);

    const int GB_G = (NGENE + 63) / 64, GB_D = (NDIS + 63) / 64;

    // ---- layer 1
    gemm_k128<128, false><<<GB_G, 256, 0, stream>>>(xg, Ws1 + 0 * 128 * 128, nullptr, hs0, NGENE);
    gemm_k128<128, false><<<GB_G, 256, 0, stream>>>(xg, Ws1 + 1 * 128 * 128, nullptr, hs1, NGENE);
    gemm_k128<128, false><<<GB_D, 256, 0, stream>>>(xd, Ws1 + 2 * 128 * 128, nullptr, hs2, NDIS);
    node_dots_gene<<<NGENE / 4, 256, 0, stream>>>(xg, av, es0, es1, ed0, ed2, NGENE);
    node_dots_dis <<<NDIS  / 4, 256, 0, stream>>>(xd, av, es2, ed1, NDIS);
    agg_gat<true><<<NGENE / 4, 256, 0, stream>>>(rowptr, col,
        0,             hs0, es0, ed0, b1 + 0 * 128,
        NGENE + NDIS,  hs2, es2, ed2, b1 + 2 * 128,
        h1g, NGENE);
    agg_gat<false><<<NDIS / 4, 256, 0, stream>>>(rowptr, col,
        NGENE, hs1, es1, ed1, b1 + 1 * 128,
        0, (const float*)nullptr, (const float*)nullptr, (const float*)nullptr, (const float*)nullptr,
        h1d, NDIS);

    // ---- layer 2 (reuses hs buffers; aggregates overwrite h1g/h1d after all reads done)
    gemm_k128<128, false><<<GB_G, 256, 0, stream>>>(h1g, Ws2 + 0 * 128 * 128, nullptr, hs0, NGENE);
    gemm_k128<128, false><<<GB_G, 256, 0, stream>>>(h1g, Ws2 + 1 * 128 * 128, nullptr, hs1, NGENE);
    gemm_k128<128, false><<<GB_D, 256, 0, stream>>>(h1d, Ws2 + 2 * 128 * 128, nullptr, hs2, NDIS);
    node_dots_gene<<<NGENE / 4, 256, 0, stream>>>(h1g, av + 6 * 128, es0, es1, ed0, ed2, NGENE);
    node_dots_dis <<<NDIS  / 4, 256, 0, stream>>>(h1d, av + 6 * 128, es2, ed1, NDIS);
    agg_gat<true><<<NGENE / 4, 256, 0, stream>>>(rowptr, col,
        0,             hs0, es0, ed0, b2 + 0 * 128,
        NGENE + NDIS,  hs2, es2, ed2, b2 + 2 * 128,
        h1g, NGENE);
    agg_gat<false><<<NDIS / 4, 256, 0, stream>>>(rowptr, col,
        NGENE, hs1, es1, ed1, b2 + 1 * 128,
        0, (const float*)nullptr, (const float*)nullptr, (const float*)nullptr, (const float*)nullptr,
        h1d, NDIS);

    // ---- output heads (write directly into d_out, gene first)
    gemm_k128<64, true><<<GB_G, 256, 0, stream>>>(h1g, Wg,  bg, out, NGENE);
    gemm_k128<64, true><<<GB_D, 256, 0, stream>>>(h1d, Wdh, bd, out + (size_t)NGENE * OUTF, NDIS);
}

// Round 3
// 660.558 us; speedup vs baseline: 2.4459x; 2.4459x over previous
//
#include <hip/hip_runtime.h>
#include <hip/hip_bf16.h>
#include <cstdint>
#include <cstddef>

#define NGENE 100000
#define NDIS  20000
#define FDIM  128
#define HIDD  128
#define OUTF  64
#define EGG   400000
#define EGD   100000
#define EDG   100000
#define ETOT  (EGG + EGD + EDG)
#define NSLOT (NGENE + NDIS + NGENE)   // g2g slots [0,NG) | g2d [NG,NG+ND) | d2g [NG+ND,...)
#define SLOPE 0.2f

typedef __attribute__((ext_vector_type(8))) short short8;
typedef __attribute__((ext_vector_type(4))) float f32x4;

static __device__ __forceinline__ float leaky(float x) { return x > 0.f ? x : SLOPE * x; }

static __device__ __forceinline__ ushort f2b(float x) {  // fp32 -> bf16 RNE
    uint u = __float_as_uint(x);
    return (ushort)((u + 0x7fffu + ((u >> 16) & 1u)) >> 16);
}
static __device__ __forceinline__ float b2f(uint s) { return __uint_as_float(s << 16); }

// ---------------------------------------------------------------- converts
__global__ __launch_bounds__(256) void conv_f32_bf16(const float* __restrict__ in,
                                                     ushort* __restrict__ out, int n4)
{
    int i = blockIdx.x * 256 + threadIdx.x;
    if (i >= n4) return;
    float4 v = ((const float4*)in)[i];
    ushort4 o; o.x = f2b(v.x); o.y = f2b(v.y); o.z = f2b(v.z); o.w = f2b(v.w);
    ((ushort4*)out)[i] = o;
}

// W [128(k) x C] fp32 -> Wt [C x 128(k)] bf16
__global__ __launch_bounds__(256) void conv_wt(const float* __restrict__ W,
                                               ushort* __restrict__ Wt, int C)
{
    int i = blockIdx.x * 256 + threadIdx.x;     // i = c*128 + k
    if (i >= C * 128) return;
    int c = i >> 7, k = i & 127;
    Wt[i] = f2b(W[k * C + c]);
}

// ---------------------------------------------------------------- MFMA GEMM: [N,128]bf16 @ Wt[NCOL,128]bf16
// 64-row tile per block, 4 waves, wave w -> rows [16w,16w+16), all NCOL cols.
// LDS XOR-swizzle (byte ^= (row&7)<<4) on write+read kills stride-256B bank conflicts.
template<int NCOL, bool OUT_BF16>
__global__ __launch_bounds__(256) void gemm_mfma(const ushort* __restrict__ X,
                                                 const ushort* __restrict__ Wt,
                                                 const float* __restrict__ bias,
                                                 void* __restrict__ H, int N)
{
    __shared__ ushort xs[64 * 128];
    __shared__ ushort wsh[NCOL * 128];
    const int tid = threadIdx.x;
    const int r0  = blockIdx.x * 64;

    for (int ci = tid; ci < NCOL * 16; ci += 256) {        // stage W^T (16B chunks)
        int r = ci >> 4; int bc = (ci & 15) << 4;
        int4 v = *(const int4*)((const char*)Wt + r * 256 + bc);
        *(int4*)((char*)wsh + r * 256 + (bc ^ ((r & 7) << 4))) = v;
    }
    for (int ci = tid; ci < 1024; ci += 256) {             // stage X tile
        int r = ci >> 4; int bc = (ci & 15) << 4;
        int4 v = make_int4(0, 0, 0, 0);
        if (r0 + r < N) v = *(const int4*)((const char*)X + (size_t)(r0 + r) * 256 + bc);
        *(int4*)((char*)xs + r * 256 + (bc ^ ((r & 7) << 4))) = v;
    }
    __syncthreads();

    const int w = tid >> 6, l = tid & 63;
    const int lr = l & 15, lk = l >> 4;                    // lane row/col, k-group
    f32x4 acc[NCOL / 16];
    #pragma unroll
    for (int i = 0; i < NCOL / 16; ++i) acc[i] = f32x4{0.f, 0.f, 0.f, 0.f};

    #pragma unroll
    for (int ks = 0; ks < 4; ++ks) {
        int ar = w * 16 + lr;
        short8 a = *(const short8*)((const char*)xs + ar * 256 + ((ks * 64 + lk * 16) ^ ((ar & 7) << 4)));
        #pragma unroll
        for (int nt = 0; nt < NCOL / 16; ++nt) {
            int bcoln = nt * 16 + lr;
            short8 b = *(const short8*)((const char*)wsh + bcoln * 256 + ((ks * 64 + lk * 16) ^ ((bcoln & 7) << 4)));
            acc[nt] = __builtin_amdgcn_mfma_f32_16x16x32_bf16(a, b, acc[nt], 0, 0, 0);
        }
    }

    #pragma unroll
    for (int nt = 0; nt < NCOL / 16; ++nt) {
        int col = nt * 16 + lr;
        float bv = OUT_BF16 ? 0.f : bias[col];
        #pragma unroll
        for (int q = 0; q < 4; ++q) {
            int gr = r0 + w * 16 + lk * 4 + q;             // C/D: col=lane&15, row=(lane>>4)*4+reg
            if (gr < N) {
                if (OUT_BF16) ((ushort*)H)[(size_t)gr * NCOL + col] = f2b(acc[nt][q]);
                else          ((float*)H)[(size_t)gr * NCOL + col] = acc[nt][q] + bv;
            }
        }
    }
}

// ---------------------------------------------------------------- attention vectors: av[mat][f] = sum_h W[t][f][h]*a[t][h]
__global__ __launch_bounds__(64) void compute_av(const float* __restrict__ Ws1, const float* __restrict__ Wd1,
                                                 const float* __restrict__ as1, const float* __restrict__ ad1,
                                                 const float* __restrict__ Ws2, const float* __restrict__ Wd2,
                                                 const float* __restrict__ as2, const float* __restrict__ ad2,
                                                 float* __restrict__ av)
{
    int b = blockIdx.x;              // 0..1535
    int mat = b >> 7, f = b & 127;   // mat: [layer][6] ; 6 = vs0,vs1,vs2,vd0,vd1,vd2
    int layer = mat / 6, idx = mat % 6;
    int t = (idx < 3) ? idx : idx - 3;
    const float* W; const float* a;
    if (layer == 0) { W = (idx < 3) ? Ws1 : Wd1; a = (idx < 3) ? as1 : ad1; }
    else           { W = (idx < 3) ? Ws2 : Wd2; a = (idx < 3) ? as2 : ad2; }
    const float* Wrow = W + ((size_t)t * 128 + f) * 128;
    const float* avec = a + t * 128;
    int lane = threadIdx.x;
    float2 w  = ((const float2*)Wrow)[lane];
    float2 aa = ((const float2*)avec)[lane];
    float d = w.x * aa.x + w.y * aa.y;
    for (int off = 32; off; off >>= 1) d += __shfl_down(d, off);
    if (lane == 0) av[mat * 128 + f] = d;
}

// ---------------------------------------------------------------- per-node scalar dots (fp32 input, layer 1)
__global__ __launch_bounds__(256) void node_dots_gene(const float* __restrict__ X, const float* __restrict__ av,
                                                      float* __restrict__ es0, float* __restrict__ es1,
                                                      float* __restrict__ ed0, float* __restrict__ ed2, int N)
{
    int n = blockIdx.x * 4 + (threadIdx.x >> 6);
    if (n >= N) return;
    int lane = threadIdx.x & 63;
    float2 x  = ((const float2*)(X + (size_t)n * 128))[lane];
    float2 a0 = ((const float2*)(av + 0 * 128))[lane];
    float2 a1 = ((const float2*)(av + 1 * 128))[lane];
    float2 a3 = ((const float2*)(av + 3 * 128))[lane];
    float2 a5 = ((const float2*)(av + 5 * 128))[lane];
    float d0 = x.x * a0.x + x.y * a0.y;
    float d1 = x.x * a1.x + x.y * a1.y;
    float d3 = x.x * a3.x + x.y * a3.y;
    float d5 = x.x * a5.x + x.y * a5.y;
    for (int off = 32; off; off >>= 1) {
        d0 += __shfl_down(d0, off);
        d1 += __shfl_down(d1, off);
        d3 += __shfl_down(d3, off);
        d5 += __shfl_down(d5, off);
    }
    if (lane == 0) { es0[n] = d0; es1[n] = d1; ed0[n] = d3; ed2[n] = d5; }
}

__global__ __launch_bounds__(256) void node_dots_dis(const float* __restrict__ X, const float* __restrict__ av,
                                                     float* __restrict__ es2, float* __restrict__ ed1, int N)
{
    int n = blockIdx.x * 4 + (threadIdx.x >> 6);
    if (n >= N) return;
    int lane = threadIdx.x & 63;
    float2 x  = ((const float2*)(X + (size_t)n * 128))[lane];
    float2 a2 = ((const float2*)(av + 2 * 128))[lane];
    float2 a4 = ((const float2*)(av + 4 * 128))[lane];
    float d2 = x.x * a2.x + x.y * a2.y;
    float d4 = x.x * a4.x + x.y * a4.y;
    for (int off = 32; off; off >>= 1) {
        d2 += __shfl_down(d2, off);
        d4 += __shfl_down(d4, off);
    }
    if (lane == 0) { es2[n] = d2; ed1[n] = d4; }
}

// ---- bf16-input variants (layer 2)
__global__ __launch_bounds__(256) void node_dots_gene_b(const ushort* __restrict__ X, const float* __restrict__ av,
                                                        float* __restrict__ es0, float* __restrict__ es1,
                                                        float* __restrict__ ed0, float* __restrict__ ed2, int N)
{
    int n = blockIdx.x * 4 + (threadIdx.x >> 6);
    if (n >= N) return;
    int lane = threadIdx.x & 63;
    uint u = ((const uint*)(X + (size_t)n * 128))[lane];
    float x0 = b2f(u & 0xffffu), x1 = b2f(u >> 16);
    float2 a0 = ((const float2*)(av + 0 * 128))[lane];
    float2 a1 = ((const float2*)(av + 1 * 128))[lane];
    float2 a3 = ((const float2*)(av + 3 * 128))[lane];
    float2 a5 = ((const float2*)(av + 5 * 128))[lane];
    float d0 = x0 * a0.x + x1 * a0.y;
    float d1 = x0 * a1.x + x1 * a1.y;
    float d3 = x0 * a3.x + x1 * a3.y;
    float d5 = x0 * a5.x + x1 * a5.y;
    for (int off = 32; off; off >>= 1) {
        d0 += __shfl_down(d0, off);
        d1 += __shfl_down(d1, off);
        d3 += __shfl_down(d3, off);
        d5 += __shfl_down(d5, off);
    }
    if (lane == 0) { es0[n] = d0; es1[n] = d1; ed0[n] = d3; ed2[n] = d5; }
}

__global__ __launch_bounds__(256) void node_dots_dis_b(const ushort* __restrict__ X, const float* __restrict__ av,
                                                       float* __restrict__ es2, float* __restrict__ ed1, int N)
{
    int n = blockIdx.x * 4 + (threadIdx.x >> 6);
    if (n >= N) return;
    int lane = threadIdx.x & 63;
    uint u = ((const uint*)(X + (size_t)n * 128))[lane];
    float x0 = b2f(u & 0xffffu), x1 = b2f(u >> 16);
    float2 a2 = ((const float2*)(av + 2 * 128))[lane];
    float2 a4 = ((const float2*)(av + 4 * 128))[lane];
    float d2 = x0 * a2.x + x1 * a2.y;
    float d4 = x0 * a4.x + x1 * a4.y;
    for (int off = 32; off; off >>= 1) {
        d2 += __shfl_down(d2, off);
        d4 += __shfl_down(d4, off);
    }
    if (lane == 0) { es2[n] = d2; ed1[n] = d4; }
}

// ---------------------------------------------------------------- CSR build
__global__ void hist_edges(const int* __restrict__ gg_d, const int* __restrict__ gd_d,
                           const int* __restrict__ dg_d, int* __restrict__ counts)
{
    int i = blockIdx.x * blockDim.x + threadIdx.x;
    if (i >= ETOT) return;
    int slot;
    if (i < EGG) slot = gg_d[i];
    else if (i < EGG + EGD) slot = NGENE + gd_d[i - EGG];
    else slot = NGENE + NDIS + dg_d[i - EGG - EGD];
    atomicAdd(&counts[slot], 1);
}

__global__ __launch_bounds__(256) void scan_blocks(const int* __restrict__ counts, int* __restrict__ rowptr,
                                                   int* __restrict__ partials, int n)
{
    __shared__ int sdata[256];
    int base = blockIdx.x * 2048;
    int tid  = threadIdx.x;
    int local[8]; int s = 0;
    #pragma unroll
    for (int j = 0; j < 8; ++j) {
        int idx = base + tid * 8 + j;
        int v = (idx < n) ? counts[idx] : 0;
        local[j] = s; s += v;
    }
    sdata[tid] = s;
    __syncthreads();
    for (int off = 1; off < 256; off <<= 1) {
        int v = 0;
        if (tid >= off) v = sdata[tid - off];
        __syncthreads();
        if (tid >= off) sdata[tid] += v;
        __syncthreads();
    }
    int texcl = (tid ? sdata[tid - 1] : 0);
    #pragma unroll
    for (int j = 0; j < 8; ++j) {
        int idx = base + tid * 8 + j;
        if (idx < n) rowptr[idx] = local[j] + texcl;
    }
    if (tid == 255) partials[blockIdx.x] = sdata[255];
}

__global__ __launch_bounds__(256) void scan_partials(int* __restrict__ partials, int nb)
{
    __shared__ int sdata[256];
    int tid = threadIdx.x;
    sdata[tid] = (tid < nb) ? partials[tid] : 0;
    __syncthreads();
    for (int off = 1; off < 256; off <<= 1) {
        int v = 0;
        if (tid >= off) v = sdata[tid - off];
        __syncthreads();
        if (tid >= off) sdata[tid] += v;
        __syncthreads();
    }
    partials[tid] = (tid ? sdata[tid - 1] : 0);
}

__global__ void scan_add(int* __restrict__ rowptr, const int* __restrict__ partials, int n)
{
    int i = blockIdx.x * blockDim.x + threadIdx.x;
    if (i < n) rowptr[i] += partials[i >> 11];
    if (i == 0) rowptr[n] = ETOT;
}

__global__ void scatter_edges(const int* __restrict__ gg_s, const int* __restrict__ gg_d,
                              const int* __restrict__ gd_s, const int* __restrict__ gd_d,
                              const int* __restrict__ dg_s, const int* __restrict__ dg_d,
                              const int* __restrict__ rowptr, int* __restrict__ cursor, int* __restrict__ col)
{
    int i = blockIdx.x * blockDim.x + threadIdx.x;
    if (i >= ETOT) return;
    int slot, src;
    if (i < EGG) { slot = gg_d[i]; src = gg_s[i]; }
    else if (i < EGG + EGD) { int j = i - EGG; slot = NGENE + gd_d[j]; src = gd_s[j]; }
    else { int j = i - EGG - EGD; slot = NGENE + NDIS + dg_d[j]; src = dg_s[j]; }
    int pos = atomicAdd(&cursor[slot], 1);
    col[rowptr[slot] + pos] = src;
}

// ---------------------------------------------------------------- softmax-aggregate (wave per dst node, bf16 hs)
__device__ __forceinline__ void seg_accum_b(const int* __restrict__ rowptr, const int* __restrict__ col,
                                            int slot, const ushort* __restrict__ hs,
                                            const float* __restrict__ es, float edv,
                                            int lane, float& ax, float& ay)
{
    int s = rowptr[slot], e = rowptr[slot + 1];
    if (e <= s) return;
    float m = -1e30f;
    for (int i = s; i < e; ++i) m = fmaxf(m, leaky(es[col[i]] + edv));
    float denom = 0.f; float sx = 0.f, sy = 0.f;
    for (int i = s; i < e; ++i) {
        int sn = col[i];
        float p = __expf(leaky(es[sn] + edv) - m);
        denom += p;
        uint u = ((const uint*)(hs + (size_t)sn * HIDD))[lane];
        sx += p * b2f(u & 0xffffu); sy += p * b2f(u >> 16);
    }
    float inv = 1.0f / denom;
    ax += sx * inv; ay += sy * inv;
}

template<bool TWO>
__global__ __launch_bounds__(256) void agg_gat_b(const int* __restrict__ rowptr, const int* __restrict__ col,
    int baseA, const ushort* __restrict__ hsA, const float* __restrict__ esA, const float* __restrict__ edA,
    const float* __restrict__ biasA,
    int baseB, const ushort* __restrict__ hsB, const float* __restrict__ esB, const float* __restrict__ edB,
    const float* __restrict__ biasB,
    ushort* __restrict__ out, int N)
{
    int wid = blockIdx.x * 4 + (threadIdx.x >> 6);
    if (wid >= N) return;
    int lane = threadIdx.x & 63;
    float ax = 0.f, ay = 0.f;
    seg_accum_b(rowptr, col, baseA + wid, hsA, esA, edA[wid], lane, ax, ay);
    if (TWO) seg_accum_b(rowptr, col, baseB + wid, hsB, esB, edB[wid], lane, ax, ay);
    int c = lane * 2;
    float bx = biasA[c]     + (TWO ? biasB[c]     : 0.f);
    float by = biasA[c + 1] + (TWO ? biasB[c + 1] : 0.f);
    uint lo = f2b(fmaxf(ax + bx, 0.f));
    uint hi = f2b(fmaxf(ay + by, 0.f));
    ((uint*)out)[(size_t)wid * (HIDD / 2) + lane] = lo | (hi << 16);
}

// ---------------------------------------------------------------- launch
extern "C" void kernel_launch(void* const* d_in, const int* in_sizes, int n_in,
                              void* d_out, int out_size, void* d_ws, size_t ws_size,
                              hipStream_t stream)
{
    const float* xg  = (const float*)d_in[0];
    const float* xd  = (const float*)d_in[1];
    const float* Ws1 = (const float*)d_in[2];
    const float* Wd1 = (const float*)d_in[3];
    const float* as1 = (const float*)d_in[4];
    const float* ad1 = (const float*)d_in[5];
    const float* b1  = (const float*)d_in[6];
    const float* Ws2 = (const float*)d_in[7];
    const float* Wd2 = (const float*)d_in[8];
    const float* as2 = (const float*)d_in[9];
    const float* ad2 = (const float*)d_in[10];
    const float* b2  = (const float*)d_in[11];
    const float* Wg  = (const float*)d_in[12];
    const float* bg  = (const float*)d_in[13];
    const float* Wdh = (const float*)d_in[14];
    const float* bd  = (const float*)d_in[15];
    const int* gg_s = (const int*)d_in[16];
    const int* gg_d = (const int*)d_in[17];
    const int* gd_s = (const int*)d_in[18];
    const int* gd_d = (const int*)d_in[19];
    const int* dg_s = (const int*)d_in[20];
    const int* dg_d = (const int*)d_in[21];
    float* out = (float*)d_out;

    size_t p = 0;
    char* ws = (char*)d_ws;
    auto alloc_f = [&](size_t n) { p = (p + 255) & ~(size_t)255; float* r = (float*)(ws + p);  p += n * sizeof(float);  return r; };
    auto alloc_i = [&](size_t n) { p = (p + 255) & ~(size_t)255; int* r = (int*)(ws + p);      p += n * sizeof(int);    return r; };
    auto alloc_u = [&](size_t n) { p = (p + 255) & ~(size_t)255; ushort* r = (ushort*)(ws + p); p += n * sizeof(ushort); return r; };

    ushort* xgb  = alloc_u((size_t)NGENE * FDIM);
    ushort* xdb  = alloc_u((size_t)NDIS  * FDIM);
    ushort* hs0b = alloc_u((size_t)NGENE * HIDD);
    ushort* hs1b = alloc_u((size_t)NGENE * HIDD);
    ushort* hs2b = alloc_u((size_t)NDIS  * HIDD);
    ushort* h1gb = alloc_u((size_t)NGENE * HIDD);
    ushort* h1db = alloc_u((size_t)NDIS  * HIDD);
    ushort* wt1  = alloc_u(3 * 128 * 128);
    ushort* wt2  = alloc_u(3 * 128 * 128);
    ushort* wtg  = alloc_u(64 * 128);
    ushort* wtd  = alloc_u(64 * 128);
    float* av  = alloc_f(12 * 128);
    float* es0 = alloc_f(NGENE);
    float* es1 = alloc_f(NGENE);
    float* ed0 = alloc_f(NGENE);
    float* ed2 = alloc_f(NGENE);
    float* es2 = alloc_f(NDIS);
    float* ed1 = alloc_f(NDIS);
    int* counts   = alloc_i(NSLOT);
    int* rowptr   = alloc_i(NSLOT + 1);
    int* partials = alloc_i(256);
    int* col      = alloc_i(ETOT);
    (void)ws_size; (void)in_sizes; (void)n_in; (void)out_size;

    const int SCAN_BLOCKS = (NSLOT + 2047) / 2048;   // 108

    // ---- CSR build (shared by both layers)
    hipMemsetAsync(counts, 0, (size_t)NSLOT * sizeof(int), stream);
    hist_edges<<<(ETOT + 255) / 256, 256, 0, stream>>>(gg_d, gd_d, dg_d, counts);
    scan_blocks<<<SCAN_BLOCKS, 256, 0, stream>>>(counts, rowptr, partials, NSLOT);
    scan_partials<<<1, 256, 0, stream>>>(partials, SCAN_BLOCKS);
    scan_add<<<(NSLOT + 255) / 256, 256, 0, stream>>>(rowptr, partials, NSLOT);
    hipMemsetAsync(counts, 0, (size_t)NSLOT * sizeof(int), stream);
    scatter_edges<<<(ETOT + 255) / 256, 256, 0, stream>>>(gg_s, gg_d, gd_s, gd_d, dg_s, dg_d,
                                                          rowptr, counts, col);

    // ---- bf16 conversions
    conv_f32_bf16<<<(NGENE * FDIM / 4 + 255) / 256, 256, 0, stream>>>(xg, xgb, NGENE * FDIM / 4);
    conv_f32_bf16<<<(NDIS  * FDIM / 4 + 255) / 256, 256, 0, stream>>>(xd, xdb, NDIS * FDIM / 4);
    for (int t = 0; t < 3; ++t) {
        conv_wt<<<64, 256, 0, stream>>>(Ws1 + (size_t)t * 128 * 128, wt1 + (size_t)t * 128 * 128, 128);
        conv_wt<<<64, 256, 0, stream>>>(Ws2 + (size_t)t * 128 * 128, wt2 + (size_t)t * 128 * 128, 128);
    }
    conv_wt<<<32, 256, 0, stream>>>(Wg,  wtg, 64);
    conv_wt<<<32, 256, 0, stream>>>(Wdh, wtd, 64);

    // ---- attention vectors for both layers (fp32)
    compute_av<<<1536, 64, 0, stream>>>(Ws1, Wd1, as1, ad1, Ws2, Wd2, as2, ad2, av);

    const int GB_G = (NGENE + 63) / 64, GB_D = (NDIS + 63) / 64;

    // ---- layer 1
    gemm_mfma<128, true><<<GB_G, 256, 0, stream>>>(xgb, wt1 + 0 * 128 * 128, nullptr, hs0b, NGENE);
    gemm_mfma<128, true><<<GB_G, 256, 0, stream>>>(xgb, wt1 + 1 * 128 * 128, nullptr, hs1b, NGENE);
    gemm_mfma<128, true><<<GB_D, 256, 0, stream>>>(xdb, wt1 + 2 * 128 * 128, nullptr, hs2b, NDIS);
    node_dots_gene<<<NGENE / 4, 256, 0, stream>>>(xg, av, es0, es1, ed0, ed2, NGENE);
    node_dots_dis <<<NDIS  / 4, 256, 0, stream>>>(xd, av, es2, ed1, NDIS);
    agg_gat_b<true><<<NGENE / 4, 256, 0, stream>>>(rowptr, col,
        0,             hs0b, es0, ed0, b1 + 0 * 128,
        NGENE + NDIS,  hs2b, es2, ed2, b1 + 2 * 128,
        h1gb, NGENE);
    agg_gat_b<false><<<NDIS / 4, 256, 0, stream>>>(rowptr, col,
        NGENE, hs1b, es1, ed1, b1 + 1 * 128,
        0, (const ushort*)nullptr, (const float*)nullptr, (const float*)nullptr, (const float*)nullptr,
        h1db, NDIS);

    // ---- layer 2
    gemm_mfma<128, true><<<GB_G, 256, 0, stream>>>(h1gb, wt2 + 0 * 128 * 128, nullptr, hs0b, NGENE);
    gemm_mfma<128, true><<<GB_G, 256, 0, stream>>>(h1gb, wt2 + 1 * 128 * 128, nullptr, hs1b, NGENE);
    gemm_mfma<128, true><<<GB_D, 256, 0, stream>>>(h1db, wt2 + 2 * 128 * 128, nullptr, hs2b, NDIS);
    node_dots_gene_b<<<NGENE / 4, 256, 0, stream>>>(h1gb, av + 6 * 128, es0, es1, ed0, ed2, NGENE);
    node_dots_dis_b <<<NDIS  / 4, 256, 0, stream>>>(h1db, av + 6 * 128, es2, ed1, NDIS);
    agg_gat_b<true><<<NGENE / 4, 256, 0, stream>>>(rowptr, col,
        0,             hs0b, es0, ed0, b2 + 0 * 128,
        NGENE + NDIS,  hs2b, es2, ed2, b2 + 2 * 128,
        h1gb, NGENE);
    agg_gat_b<false><<<NDIS / 4, 256, 0, stream>>>(rowptr, col,
        NGENE, hs1b, es1, ed1, b2 + 1 * 128,
        0, (const ushort*)nullptr, (const float*)nullptr, (const float*)nullptr, (const float*)nullptr,
        h1db, NDIS);

    // ---- output heads (bf16 MFMA, fp32 out + bias, gene first)
    gemm_mfma<64, false><<<GB_G, 256, 0, stream>>>(h1gb, wtg, bg, out, NGENE);
    gemm_mfma<64, false><<<GB_D, 256, 0, stream>>>(h1db, wtd, bd, out + (size_t)NGENE * OUTF, NDIS);
}

// Round 4
// 543.515 us; speedup vs baseline: 2.9725x; 1.2153x over previous
//
#include <hip/hip_runtime.h>
#include <hip/hip_bf16.h>
#include <cstdint>
#include <cstddef>

#define NGENE 100000
#define NDIS  20000
#define FDIM  128
#define HIDD  128
#define OUTF  64
#define EGG   400000
#define EGD   100000
#define EDG   100000
#define ETOT  (EGG + EGD + EDG)
#define NSLOT (NGENE + NDIS + NGENE)   // g2g slots [0,NG) | g2d [NG,NG+ND) | d2g [NG+ND,...)
#define NSRC  (2 * NGENE + NDIS)       // unified source space: [gene-as-t0 | gene-as-t1 | dis-as-t2]
#define SLOPE 0.2f

typedef __attribute__((ext_vector_type(8))) short short8;
typedef __attribute__((ext_vector_type(4))) float f32x4;

static __device__ __forceinline__ float leaky(float x) { return x > 0.f ? x : SLOPE * x; }

static __device__ __forceinline__ ushort f2b(float x) {  // fp32 -> bf16 RNE
    uint u = __float_as_uint(x);
    return (ushort)((u + 0x7fffu + ((u >> 16) & 1u)) >> 16);
}
static __device__ __forceinline__ float b2f(uint s) { return __uint_as_float(s << 16); }
static __device__ __forceinline__ uint pack2(float lo, float hi) {
    return (uint)f2b(lo) | ((uint)f2b(hi) << 16);
}

// ---------------------------------------------------------------- converts
__global__ __launch_bounds__(256) void conv_f32_bf16(const float* __restrict__ in,
                                                     ushort* __restrict__ out, int n4)
{
    int i = blockIdx.x * 256 + threadIdx.x;
    if (i >= n4) return;
    float4 v = ((const float4*)in)[i];
    ushort4 o; o.x = f2b(v.x); o.y = f2b(v.y); o.z = f2b(v.z); o.w = f2b(v.w);
    ((ushort4*)out)[i] = o;
}

// W [128(k) x C] fp32 -> Wt [C x 128(k)] bf16
__global__ __launch_bounds__(256) void conv_wt(const float* __restrict__ W,
                                               ushort* __restrict__ Wt, int C)
{
    int i = blockIdx.x * 256 + threadIdx.x;     // i = c*128 + k
    if (i >= C * 128) return;
    int c = i >> 7, k = i & 127;
    Wt[i] = f2b(W[k * C + c]);
}

// ---------------------------------------------------------------- MFMA GEMM: [N,128]bf16 @ Wt[NCOL,128]bf16
template<int NCOL, bool OUT_BF16>
__global__ __launch_bounds__(256) void gemm_mfma(const ushort* __restrict__ X,
                                                 const ushort* __restrict__ Wt,
                                                 const float* __restrict__ bias,
                                                 void* __restrict__ H, int N)
{
    __shared__ ushort xs[64 * 128];
    __shared__ ushort wsh[NCOL * 128];
    const int tid = threadIdx.x;
    const int r0  = blockIdx.x * 64;

    for (int ci = tid; ci < NCOL * 16; ci += 256) {        // stage W^T (16B chunks)
        int r = ci >> 4; int bc = (ci & 15) << 4;
        int4 v = *(const int4*)((const char*)Wt + r * 256 + bc);
        *(int4*)((char*)wsh + r * 256 + (bc ^ ((r & 7) << 4))) = v;
    }
    for (int ci = tid; ci < 1024; ci += 256) {             // stage X tile
        int r = ci >> 4; int bc = (ci & 15) << 4;
        int4 v = make_int4(0, 0, 0, 0);
        if (r0 + r < N) v = *(const int4*)((const char*)X + (size_t)(r0 + r) * 256 + bc);
        *(int4*)((char*)xs + r * 256 + (bc ^ ((r & 7) << 4))) = v;
    }
    __syncthreads();

    const int w = tid >> 6, l = tid & 63;
    const int lr = l & 15, lk = l >> 4;
    f32x4 acc[NCOL / 16];
    #pragma unroll
    for (int i = 0; i < NCOL / 16; ++i) acc[i] = f32x4{0.f, 0.f, 0.f, 0.f};

    #pragma unroll
    for (int ks = 0; ks < 4; ++ks) {
        int ar = w * 16 + lr;
        short8 a = *(const short8*)((const char*)xs + ar * 256 + ((ks * 64 + lk * 16) ^ ((ar & 7) << 4)));
        #pragma unroll
        for (int nt = 0; nt < NCOL / 16; ++nt) {
            int bcoln = nt * 16 + lr;
            short8 b = *(const short8*)((const char*)wsh + bcoln * 256 + ((ks * 64 + lk * 16) ^ ((bcoln & 7) << 4)));
            acc[nt] = __builtin_amdgcn_mfma_f32_16x16x32_bf16(a, b, acc[nt], 0, 0, 0);
        }
    }

    #pragma unroll
    for (int nt = 0; nt < NCOL / 16; ++nt) {
        int col = nt * 16 + lr;
        float bv = OUT_BF16 ? 0.f : bias[col];
        #pragma unroll
        for (int q = 0; q < 4; ++q) {
            int gr = r0 + w * 16 + lk * 4 + q;             // C/D: col=lane&15, row=(lane>>4)*4+reg
            if (gr < N) {
                if (OUT_BF16) ((ushort*)H)[(size_t)gr * NCOL + col] = f2b(acc[nt][q]);
                else          ((float*)H)[(size_t)gr * NCOL + col] = acc[nt][q] + bv;
            }
        }
    }
}

// ---------------------------------------------------------------- attention vectors: av[mat][f] = sum_h W[t][f][h]*a[t][h]
__global__ __launch_bounds__(64) void compute_av(const float* __restrict__ Ws1, const float* __restrict__ Wd1,
                                                 const float* __restrict__ as1, const float* __restrict__ ad1,
                                                 const float* __restrict__ Ws2, const float* __restrict__ Wd2,
                                                 const float* __restrict__ as2, const float* __restrict__ ad2,
                                                 float* __restrict__ av)
{
    int b = blockIdx.x;              // 0..1535
    int mat = b >> 7, f = b & 127;
    int layer = mat / 6, idx = mat % 6;
    int t = (idx < 3) ? idx : idx - 3;
    const float* W; const float* a;
    if (layer == 0) { W = (idx < 3) ? Ws1 : Wd1; a = (idx < 3) ? as1 : ad1; }
    else           { W = (idx < 3) ? Ws2 : Wd2; a = (idx < 3) ? as2 : ad2; }
    const float* Wrow = W + ((size_t)t * 128 + f) * 128;
    const float* avec = a + t * 128;
    int lane = threadIdx.x;
    float2 w  = ((const float2*)Wrow)[lane];
    float2 aa = ((const float2*)avec)[lane];
    float d = w.x * aa.x + w.y * aa.y;
    for (int off = 32; off; off >>= 1) d += __shfl_down(d, off);
    if (lane == 0) av[mat * 128 + f] = d;
}

// ---------------------------------------------------------------- per-node scalar dots (bf16 input)
__global__ __launch_bounds__(256) void node_dots_gene_b(const ushort* __restrict__ X, const float* __restrict__ av,
                                                        float* __restrict__ es0, float* __restrict__ es1,
                                                        float* __restrict__ ed0, float* __restrict__ ed2, int N)
{
    int n = blockIdx.x * 4 + (threadIdx.x >> 6);
    if (n >= N) return;
    int lane = threadIdx.x & 63;
    uint u = ((const uint*)(X + (size_t)n * 128))[lane];
    float x0 = b2f(u & 0xffffu), x1 = b2f(u >> 16);
    float2 a0 = ((const float2*)(av + 0 * 128))[lane];
    float2 a1 = ((const float2*)(av + 1 * 128))[lane];
    float2 a3 = ((const float2*)(av + 3 * 128))[lane];
    float2 a5 = ((const float2*)(av + 5 * 128))[lane];
    float d0 = x0 * a0.x + x1 * a0.y;
    float d1 = x0 * a1.x + x1 * a1.y;
    float d3 = x0 * a3.x + x1 * a3.y;
    float d5 = x0 * a5.x + x1 * a5.y;
    for (int off = 32; off; off >>= 1) {
        d0 += __shfl_down(d0, off);
        d1 += __shfl_down(d1, off);
        d3 += __shfl_down(d3, off);
        d5 += __shfl_down(d5, off);
    }
    if (lane == 0) { es0[n] = d0; es1[n] = d1; ed0[n] = d3; ed2[n] = d5; }
}

__global__ __launch_bounds__(256) void node_dots_dis_b(const ushort* __restrict__ X, const float* __restrict__ av,
                                                       float* __restrict__ es2, float* __restrict__ ed1, int N)
{
    int n = blockIdx.x * 4 + (threadIdx.x >> 6);
    if (n >= N) return;
    int lane = threadIdx.x & 63;
    uint u = ((const uint*)(X + (size_t)n * 128))[lane];
    float x0 = b2f(u & 0xffffu), x1 = b2f(u >> 16);
    float2 a2 = ((const float2*)(av + 2 * 128))[lane];
    float2 a4 = ((const float2*)(av + 4 * 128))[lane];
    float d2 = x0 * a2.x + x1 * a2.y;
    float d4 = x0 * a4.x + x1 * a4.y;
    for (int off = 32; off; off >>= 1) {
        d2 += __shfl_down(d2, off);
        d4 += __shfl_down(d4, off);
    }
    if (lane == 0) { es2[n] = d2; ed1[n] = d4; }
}

// ---------------------------------------------------------------- CSR build
__global__ void hist_edges(const int* __restrict__ gg_d, const int* __restrict__ gd_d,
                           const int* __restrict__ dg_d, int* __restrict__ counts)
{
    int i = blockIdx.x * blockDim.x + threadIdx.x;
    if (i >= ETOT) return;
    int slot;
    if (i < EGG) slot = gg_d[i];
    else if (i < EGG + EGD) slot = NGENE + gd_d[i - EGG];
    else slot = NGENE + NDIS + dg_d[i - EGG - EGD];
    atomicAdd(&counts[slot], 1);
}

__global__ __launch_bounds__(256) void scan_blocks(const int* __restrict__ counts, int* __restrict__ rowptr,
                                                   int* __restrict__ partials, int n)
{
    __shared__ int sdata[256];
    int base = blockIdx.x * 2048;
    int tid  = threadIdx.x;
    int local[8]; int s = 0;
    #pragma unroll
    for (int j = 0; j < 8; ++j) {
        int idx = base + tid * 8 + j;
        int v = (idx < n) ? counts[idx] : 0;
        local[j] = s; s += v;
    }
    sdata[tid] = s;
    __syncthreads();
    for (int off = 1; off < 256; off <<= 1) {
        int v = 0;
        if (tid >= off) v = sdata[tid - off];
        __syncthreads();
        if (tid >= off) sdata[tid] += v;
        __syncthreads();
    }
    int texcl = (tid ? sdata[tid - 1] : 0);
    #pragma unroll
    for (int j = 0; j < 8; ++j) {
        int idx = base + tid * 8 + j;
        if (idx < n) rowptr[idx] = local[j] + texcl;
    }
    if (tid == 255) partials[blockIdx.x] = sdata[255];
}

__global__ __launch_bounds__(256) void scan_partials(int* __restrict__ partials, int nb)
{
    __shared__ int sdata[256];
    int tid = threadIdx.x;
    sdata[tid] = (tid < nb) ? partials[tid] : 0;
    __syncthreads();
    for (int off = 1; off < 256; off <<= 1) {
        int v = 0;
        if (tid >= off) v = sdata[tid - off];
        __syncthreads();
        if (tid >= off) sdata[tid] += v;
        __syncthreads();
    }
    partials[tid] = (tid ? sdata[tid - 1] : 0);
}

__global__ void scan_add(int* __restrict__ rowptr, const int* __restrict__ partials, int n)
{
    int i = blockIdx.x * blockDim.x + threadIdx.x;
    if (i < n) rowptr[i] += partials[i >> 11];
    if (i == 0) rowptr[n] = ETOT;
}

// scatter with unified source index + row (slot) per entry
__global__ void scatter_edges(const int* __restrict__ gg_s, const int* __restrict__ gg_d,
                              const int* __restrict__ gd_s, const int* __restrict__ gd_d,
                              const int* __restrict__ dg_s, const int* __restrict__ dg_d,
                              const int* __restrict__ rowptr, int* __restrict__ cursor,
                              int* __restrict__ colu, int* __restrict__ rowarr)
{
    int i = blockIdx.x * blockDim.x + threadIdx.x;
    if (i >= ETOT) return;
    int slot, srcu;
    if (i < EGG) { slot = gg_d[i]; srcu = gg_s[i]; }
    else if (i < EGG + EGD) { int j = i - EGG; slot = NGENE + gd_d[j]; srcu = NGENE + gd_s[j]; }
    else { int j = i - EGG - EGD; slot = NGENE + NDIS + dg_d[j]; srcu = 2 * NGENE + dg_s[j]; }
    int pos = atomicAdd(&cursor[slot], 1);
    int idx = rowptr[slot] + pos;
    colu[idx] = srcu;
    rowarr[idx] = slot;
}

// ---------------------------------------------------------------- edge weights (skip-max softmax numerator + denom)
__global__ __launch_bounds__(256) void edge_weights(const int* __restrict__ colu, const int* __restrict__ rowarr,
                                                    const float* __restrict__ su, const float* __restrict__ edu,
                                                    float* __restrict__ pw, float* __restrict__ denom)
{
    int i = blockIdx.x * 256 + threadIdx.x;
    if (i >= ETOT) return;
    int c = colu[i], r = rowarr[i];
    float e = leaky(su[c] + edu[r]);
    float p = __expf(fminf(e, 80.f));
    pw[i] = p;
    atomicAdd(&denom[r], p);
}

// ---------------------------------------------------------------- aggregate: 16 lanes/node, 4 nodes/wave, pipelined
__device__ __forceinline__ void seg_go(int slot, const int* __restrict__ rowptr,
                                       const int* __restrict__ colu, const float* __restrict__ pw,
                                       const float* __restrict__ denom, const uint4* __restrict__ hsu,
                                       int gl, float acc[8])
{
    int s = rowptr[slot], e = rowptr[slot + 1];
    if (e <= s) return;
    float sx[8];
    #pragma unroll
    for (int j = 0; j < 8; ++j) sx[j] = 0.f;
    int i = s;
    int c = colu[i]; float p = pw[i];
    uint4 h = hsu[(size_t)c * 16 + gl];
    for (++i; i < e; ++i) {
        int c1 = colu[i]; float p1 = pw[i];
        uint4 h1 = hsu[(size_t)c1 * 16 + gl];      // in flight while we consume h
        sx[0] += p * b2f(h.x & 0xffffu); sx[1] += p * b2f(h.x >> 16);
        sx[2] += p * b2f(h.y & 0xffffu); sx[3] += p * b2f(h.y >> 16);
        sx[4] += p * b2f(h.z & 0xffffu); sx[5] += p * b2f(h.z >> 16);
        sx[6] += p * b2f(h.w & 0xffffu); sx[7] += p * b2f(h.w >> 16);
        p = p1; h = h1;
    }
    sx[0] += p * b2f(h.x & 0xffffu); sx[1] += p * b2f(h.x >> 16);
    sx[2] += p * b2f(h.y & 0xffffu); sx[3] += p * b2f(h.y >> 16);
    sx[4] += p * b2f(h.z & 0xffffu); sx[5] += p * b2f(h.z >> 16);
    sx[6] += p * b2f(h.w & 0xffffu); sx[7] += p * b2f(h.w >> 16);
    float inv = 1.0f / denom[slot];
    #pragma unroll
    for (int j = 0; j < 8; ++j) acc[j] += sx[j] * inv;
}

template<bool TWO>
__global__ __launch_bounds__(256) void agg_seg(const int* __restrict__ rowptr, const int* __restrict__ colu,
                                              const float* __restrict__ pw, const float* __restrict__ denom,
                                              const uint4* __restrict__ hsu,
                                              int slotA0, int slotB0,
                                              const float* __restrict__ biasA, const float* __restrict__ biasB,
                                              uint4* __restrict__ out, int N)
{
    int g  = blockIdx.x * 16 + (threadIdx.x >> 4);
    int gl = threadIdx.x & 15;
    if (g >= N) return;
    float acc[8];
    #pragma unroll
    for (int j = 0; j < 8; ++j) acc[j] = 0.f;
    seg_go(slotA0 + g, rowptr, colu, pw, denom, hsu, gl, acc);
    if (TWO) seg_go(slotB0 + g, rowptr, colu, pw, denom, hsu, gl, acc);

    float4 bA0 = ((const float4*)biasA)[gl * 2];
    float4 bA1 = ((const float4*)biasA)[gl * 2 + 1];
    float b0 = bA0.x, b1 = bA0.y, b2 = bA0.z, b3 = bA0.w;
    float b4 = bA1.x, b5 = bA1.y, b6 = bA1.z, b7 = bA1.w;
    if (TWO) {
        float4 bB0 = ((const float4*)biasB)[gl * 2];
        float4 bB1 = ((const float4*)biasB)[gl * 2 + 1];
        b0 += bB0.x; b1 += bB0.y; b2 += bB0.z; b3 += bB0.w;
        b4 += bB1.x; b5 += bB1.y; b6 += bB1.z; b7 += bB1.w;
    }
    uint4 o;
    o.x = pack2(fmaxf(acc[0] + b0, 0.f), fmaxf(acc[1] + b1, 0.f));
    o.y = pack2(fmaxf(acc[2] + b2, 0.f), fmaxf(acc[3] + b3, 0.f));
    o.z = pack2(fmaxf(acc[4] + b4, 0.f), fmaxf(acc[5] + b5, 0.f));
    o.w = pack2(fmaxf(acc[6] + b6, 0.f), fmaxf(acc[7] + b7, 0.f));
    out[(size_t)g * 16 + gl] = o;
}

// ---------------------------------------------------------------- launch
extern "C" void kernel_launch(void* const* d_in, const int* in_sizes, int n_in,
                              void* d_out, int out_size, void* d_ws, size_t ws_size,
                              hipStream_t stream)
{
    const float* xg  = (const float*)d_in[0];
    const float* xd  = (const float*)d_in[1];
    const float* Ws1 = (const float*)d_in[2];
    const float* Wd1 = (const float*)d_in[3];
    const float* as1 = (const float*)d_in[4];
    const float* ad1 = (const float*)d_in[5];
    const float* b1  = (const float*)d_in[6];
    const float* Ws2 = (const float*)d_in[7];
    const float* Wd2 = (const float*)d_in[8];
    const float* as2 = (const float*)d_in[9];
    const float* ad2 = (const float*)d_in[10];
    const float* b2  = (const float*)d_in[11];
    const float* Wg  = (const float*)d_in[12];
    const float* bg  = (const float*)d_in[13];
    const float* Wdh = (const float*)d_in[14];
    const float* bd  = (const float*)d_in[15];
    const int* gg_s = (const int*)d_in[16];
    const int* gg_d = (const int*)d_in[17];
    const int* gd_s = (const int*)d_in[18];
    const int* gd_d = (const int*)d_in[19];
    const int* dg_s = (const int*)d_in[20];
    const int* dg_d = (const int*)d_in[21];
    float* out = (float*)d_out;

    size_t p = 0;
    char* ws = (char*)d_ws;
    auto alloc_f = [&](size_t n) { p = (p + 255) & ~(size_t)255; float* r = (float*)(ws + p);  p += n * sizeof(float);  return r; };
    auto alloc_i = [&](size_t n) { p = (p + 255) & ~(size_t)255; int* r = (int*)(ws + p);      p += n * sizeof(int);    return r; };
    auto alloc_u = [&](size_t n) { p = (p + 255) & ~(size_t)255; ushort* r = (ushort*)(ws + p); p += n * sizeof(ushort); return r; };

    ushort* xgb  = alloc_u((size_t)NGENE * FDIM);
    ushort* xdb  = alloc_u((size_t)NDIS  * FDIM);
    ushort* hsu  = alloc_u((size_t)NSRC * HIDD);   // [hs0 NG | hs1 NG | hs2 ND] rows
    ushort* h1gb = alloc_u((size_t)NGENE * HIDD);
    ushort* h1db = alloc_u((size_t)NDIS  * HIDD);
    ushort* wt1  = alloc_u(3 * 128 * 128);
    ushort* wt2  = alloc_u(3 * 128 * 128);
    ushort* wtg  = alloc_u(64 * 128);
    ushort* wtd  = alloc_u(64 * 128);
    float* av   = alloc_f(12 * 128);
    float* esu  = alloc_f(NSRC);        // [es0 NG | es1 NG | es2 ND]
    float* edu  = alloc_f(NSLOT);       // [ed0 NG | ed1 ND | ed2 NG], indexed by slot
    float* pw    = alloc_f(ETOT);
    float* denom = alloc_f(NSLOT);
    int* counts   = alloc_i(NSLOT);
    int* rowptr   = alloc_i(NSLOT + 1);
    int* partials = alloc_i(256);
    int* colu     = alloc_i(ETOT);
    int* rowarr   = alloc_i(ETOT);
    (void)ws_size; (void)in_sizes; (void)n_in; (void)out_size;

    const int SCAN_BLOCKS = (NSLOT + 2047) / 2048;   // 108

    ushort* hs0 = hsu;
    ushort* hs1 = hsu + (size_t)NGENE * HIDD;
    ushort* hs2 = hsu + (size_t)2 * NGENE * HIDD;
    float* es0 = esu;
    float* es1 = esu + NGENE;
    float* es2 = esu + 2 * NGENE;
    float* ed0 = edu;
    float* ed1 = edu + NGENE;
    float* ed2 = edu + NGENE + NDIS;

    // ---- CSR build (shared by both layers)
    hipMemsetAsync(counts, 0, (size_t)NSLOT * sizeof(int), stream);
    hist_edges<<<(ETOT + 255) / 256, 256, 0, stream>>>(gg_d, gd_d, dg_d, counts);
    scan_blocks<<<SCAN_BLOCKS, 256, 0, stream>>>(counts, rowptr, partials, NSLOT);
    scan_partials<<<1, 256, 0, stream>>>(partials, SCAN_BLOCKS);
    scan_add<<<(NSLOT + 255) / 256, 256, 0, stream>>>(rowptr, partials, NSLOT);
    hipMemsetAsync(counts, 0, (size_t)NSLOT * sizeof(int), stream);
    scatter_edges<<<(ETOT + 255) / 256, 256, 0, stream>>>(gg_s, gg_d, gd_s, gd_d, dg_s, dg_d,
                                                          rowptr, counts, colu, rowarr);

    // ---- bf16 conversions
    conv_f32_bf16<<<(NGENE * FDIM / 4 + 255) / 256, 256, 0, stream>>>(xg, xgb, NGENE * FDIM / 4);
    conv_f32_bf16<<<(NDIS  * FDIM / 4 + 255) / 256, 256, 0, stream>>>(xd, xdb, NDIS * FDIM / 4);
    for (int t = 0; t < 3; ++t) {
        conv_wt<<<64, 256, 0, stream>>>(Ws1 + (size_t)t * 128 * 128, wt1 + (size_t)t * 128 * 128, 128);
        conv_wt<<<64, 256, 0, stream>>>(Ws2 + (size_t)t * 128 * 128, wt2 + (size_t)t * 128 * 128, 128);
    }
    conv_wt<<<32, 256, 0, stream>>>(Wg,  wtg, 64);
    conv_wt<<<32, 256, 0, stream>>>(Wdh, wtd, 64);

    // ---- attention vectors for both layers (fp32)
    compute_av<<<1536, 64, 0, stream>>>(Ws1, Wd1, as1, ad1, Ws2, Wd2, as2, ad2, av);

    const int GB_G = (NGENE + 63) / 64, GB_D = (NDIS + 63) / 64;
    const int AB_G = (NGENE + 15) / 16, AB_D = (NDIS + 15) / 16;

    // ---- layer 1
    gemm_mfma<128, true><<<GB_G, 256, 0, stream>>>(xgb, wt1 + 0 * 128 * 128, nullptr, hs0, NGENE);
    gemm_mfma<128, true><<<GB_G, 256, 0, stream>>>(xgb, wt1 + 1 * 128 * 128, nullptr, hs1, NGENE);
    gemm_mfma<128, true><<<GB_D, 256, 0, stream>>>(xdb, wt1 + 2 * 128 * 128, nullptr, hs2, NDIS);
    node_dots_gene_b<<<(NGENE + 3) / 4, 256, 0, stream>>>(xgb, av, es0, es1, ed0, ed2, NGENE);
    node_dots_dis_b <<<(NDIS + 3) / 4, 256, 0, stream>>>(xdb, av, es2, ed1, NDIS);
    hipMemsetAsync(denom, 0, (size_t)NSLOT * sizeof(float), stream);
    edge_weights<<<(ETOT + 255) / 256, 256, 0, stream>>>(colu, rowarr, esu, edu, pw, denom);
    agg_seg<true><<<AB_G, 256, 0, stream>>>(rowptr, colu, pw, denom, (const uint4*)hsu,
        0, NGENE + NDIS, b1 + 0 * 128, b1 + 2 * 128, (uint4*)h1gb, NGENE);
    agg_seg<false><<<AB_D, 256, 0, stream>>>(rowptr, colu, pw, denom, (const uint4*)hsu,
        NGENE, 0, b1 + 1 * 128, nullptr, (uint4*)h1db, NDIS);

    // ---- layer 2
    gemm_mfma<128, true><<<GB_G, 256, 0, stream>>>(h1gb, wt2 + 0 * 128 * 128, nullptr, hs0, NGENE);
    gemm_mfma<128, true><<<GB_G, 256, 0, stream>>>(h1gb, wt2 + 1 * 128 * 128, nullptr, hs1, NGENE);
    gemm_mfma<128, true><<<GB_D, 256, 0, stream>>>(h1db, wt2 + 2 * 128 * 128, nullptr, hs2, NDIS);
    node_dots_gene_b<<<(NGENE + 3) / 4, 256, 0, stream>>>(h1gb, av + 6 * 128, es0, es1, ed0, ed2, NGENE);
    node_dots_dis_b <<<(NDIS + 3) / 4, 256, 0, stream>>>(h1db, av + 6 * 128, es2, ed1, NDIS);
    hipMemsetAsync(denom, 0, (size_t)NSLOT * sizeof(float), stream);
    edge_weights<<<(ETOT + 255) / 256, 256, 0, stream>>>(colu, rowarr, esu, edu, pw, denom);
    agg_seg<true><<<AB_G, 256, 0, stream>>>(rowptr, colu, pw, denom, (const uint4*)hsu,
        0, NGENE + NDIS, b2 + 0 * 128, b2 + 2 * 128, (uint4*)h1gb, NGENE);
    agg_seg<false><<<AB_D, 256, 0, stream>>>(rowptr, colu, pw, denom, (const uint4*)hsu,
        NGENE, 0, b2 + 1 * 128, nullptr, (uint4*)h1db, NDIS);

    // ---- output heads (bf16 MFMA, fp32 out + bias, gene first)
    gemm_mfma<64, false><<<GB_G, 256, 0, stream>>>(h1gb, wtg, bg, out, NGENE);
    gemm_mfma<64, false><<<GB_D, 256, 0, stream>>>(h1db, wtd, bd, out + (size_t)NGENE * OUTF, NDIS);
}

// Round 5
// 458.350 us; speedup vs baseline: 3.5249x; 1.1858x over previous
//
#include <hip/hip_runtime.h>
#include <hip/hip_bf16.h>
#include <cstdint>
#include <cstddef>

#define NGENE 100000
#define NDIS  20000
#define FDIM  128
#define HIDD  128
#define OUTF  64
#define EGG   400000
#define EGD   100000
#define EDG   100000
#define ETOT  (EGG + EGD + EDG)
#define NSLOT (NGENE + NDIS + NGENE)   // g2g dst [0,NG) | g2d dst [NG,NG+ND) | d2g dst [NG+ND,...)
#define NSRC  (2 * NGENE + NDIS)       // src rows: gene t0 -> 2n, gene t1 -> 2n+1, dis t2 -> 2NG+d
#define SLOPE 0.2f

typedef __attribute__((ext_vector_type(8))) short short8;
typedef __attribute__((ext_vector_type(4))) float f32x4;

static __device__ __forceinline__ float leaky(float x) { return x > 0.f ? x : SLOPE * x; }

static __device__ __forceinline__ ushort f2b(float x) {  // fp32 -> bf16 RNE
    uint u = __float_as_uint(x);
    return (ushort)((u + 0x7fffu + ((u >> 16) & 1u)) >> 16);
}
static __device__ __forceinline__ float b2f(uint s) { return __uint_as_float(s << 16); }
static __device__ __forceinline__ uint pack2(float lo, float hi) {
    return (uint)f2b(lo) | ((uint)f2b(hi) << 16);
}

// ---------------------------------------------------------------- converts
__global__ __launch_bounds__(256) void conv_f32_bf16(const float* __restrict__ in,
                                                     ushort* __restrict__ out, int n4)
{
    int i = blockIdx.x * 256 + threadIdx.x;
    if (i >= n4) return;
    float4 v = ((const float4*)in)[i];
    ushort4 o; o.x = f2b(v.x); o.y = f2b(v.y); o.z = f2b(v.z); o.w = f2b(v.w);
    ((ushort4*)out)[i] = o;
}

// all weight transposes in one launch: W [k x C] fp32 -> Wt [C x k(128)] bf16
__global__ __launch_bounds__(256) void conv_wt_all(const float* __restrict__ Ws1, const float* __restrict__ Ws2,
                                                   const float* __restrict__ Wg,  const float* __restrict__ Wd,
                                                   ushort* __restrict__ wt1, ushort* __restrict__ wt2,
                                                   ushort* __restrict__ wtg, ushort* __restrict__ wtd)
{
    int i = blockIdx.x * 256 + threadIdx.x;          // total 114688
    if (i < 49152) {
        int t = i >> 14, r = i & 16383; int c = r >> 7, k = r & 127;
        wt1[i] = f2b(Ws1[(size_t)t * 16384 + k * 128 + c]);
    } else if (i < 98304) {
        int j = i - 49152;
        int t = j >> 14, r = j & 16383; int c = r >> 7, k = r & 127;
        wt2[j] = f2b(Ws2[(size_t)t * 16384 + k * 128 + c]);
    } else if (i < 106496) {
        int j = i - 98304; int c = j >> 7, k = j & 127;
        wtg[j] = f2b(Wg[k * 64 + c]);
    } else if (i < 114688) {
        int j = i - 106496; int c = j >> 7, k = j & 127;
        wtd[j] = f2b(Wd[k * 64 + c]);
    }
}

// ---------------------------------------------------------------- attention vectors: av[mat][f] = sum_h W[t][f][h]*a[t][h]
__global__ __launch_bounds__(64) void compute_av(const float* __restrict__ Ws1, const float* __restrict__ Wd1,
                                                 const float* __restrict__ as1, const float* __restrict__ ad1,
                                                 const float* __restrict__ Ws2, const float* __restrict__ Wd2,
                                                 const float* __restrict__ as2, const float* __restrict__ ad2,
                                                 float* __restrict__ av)
{
    int b = blockIdx.x;              // 0..1535
    int mat = b >> 7, f = b & 127;   // mats: [layer][vs0,vs1,vs2,vd0,vd1,vd2]
    int layer = mat / 6, idx = mat % 6;
    int t = (idx < 3) ? idx : idx - 3;
    const float* W; const float* a;
    if (layer == 0) { W = (idx < 3) ? Ws1 : Wd1; a = (idx < 3) ? as1 : ad1; }
    else           { W = (idx < 3) ? Ws2 : Wd2; a = (idx < 3) ? as2 : ad2; }
    const float* Wrow = W + ((size_t)t * 128 + f) * 128;
    const float* avec = a + t * 128;
    int lane = threadIdx.x;
    float2 w  = ((const float2*)Wrow)[lane];
    float2 aa = ((const float2*)avec)[lane];
    float d = w.x * aa.x + w.y * aa.y;
    for (int off = 32; off; off >>= 1) d += __shfl_down(d, off);
    if (lane == 0) av[mat * 128 + f] = d;
}

// ---------------------------------------------------------------- MFMA GEMM + fused per-node dots
// [N,128]bf16 @ Wt[NCOL,128]bf16. NDOT=4: gene (es interleaved x2, ed0, ed2); NDOT=2: dis (es, ed); 0: head.
template<int NCOL, int NDOT, bool OUT_BF16>
__global__ __launch_bounds__(256) void gemm_mfma(const ushort* __restrict__ X,
                                                 const ushort* __restrict__ Wt,
                                                 const float* __restrict__ bias,
                                                 void* __restrict__ H, int N,
                                                 const float* __restrict__ av, int4 vidx,
                                                 float* __restrict__ oes,
                                                 float* __restrict__ oda,
                                                 float* __restrict__ odb)
{
    __shared__ ushort xs[64 * 128];
    __shared__ ushort wsh[NCOL * 128];
    const int tid = threadIdx.x;
    const int r0  = blockIdx.x * 64;

    for (int ci = tid; ci < NCOL * 16; ci += 256) {        // stage W^T
        int r = ci >> 4; int bc = (ci & 15) << 4;
        int4 v = *(const int4*)((const char*)Wt + r * 256 + bc);
        *(int4*)((char*)wsh + r * 256 + (bc ^ ((r & 7) << 4))) = v;
    }
    for (int ci = tid; ci < 1024; ci += 256) {             // stage X tile
        int r = ci >> 4; int bc = (ci & 15) << 4;
        int4 v = make_int4(0, 0, 0, 0);
        if (r0 + r < N) v = *(const int4*)((const char*)X + (size_t)(r0 + r) * 256 + bc);
        *(int4*)((char*)xs + r * 256 + (bc ^ ((r & 7) << 4))) = v;
    }
    __syncthreads();

    const int w = tid >> 6, l = tid & 63;
    const int lr = l & 15, lk = l >> 4;
    f32x4 acc[NCOL / 16];
    #pragma unroll
    for (int i = 0; i < NCOL / 16; ++i) acc[i] = f32x4{0.f, 0.f, 0.f, 0.f};

    #pragma unroll
    for (int ks = 0; ks < 4; ++ks) {
        int ar = w * 16 + lr;
        short8 a = *(const short8*)((const char*)xs + ar * 256 + ((ks * 64 + lk * 16) ^ ((ar & 7) << 4)));
        #pragma unroll
        for (int nt = 0; nt < NCOL / 16; ++nt) {
            int bcoln = nt * 16 + lr;
            short8 b = *(const short8*)((const char*)wsh + bcoln * 256 + ((ks * 64 + lk * 16) ^ ((bcoln & 7) << 4)));
            acc[nt] = __builtin_amdgcn_mfma_f32_16x16x32_bf16(a, b, acc[nt], 0, 0, 0);
        }
    }

    #pragma unroll
    for (int nt = 0; nt < NCOL / 16; ++nt) {
        int col = nt * 16 + lr;
        float bv = OUT_BF16 ? 0.f : bias[col];
        #pragma unroll
        for (int q = 0; q < 4; ++q) {
            int gr = r0 + w * 16 + lk * 4 + q;             // C/D: col=lane&15, row=(lane>>4)*4+reg
            if (gr < N) {
                if (OUT_BF16) ((ushort*)H)[(size_t)gr * NCOL + col] = f2b(acc[nt][q]);
                else          ((float*)H)[(size_t)gr * NCOL + col] = acc[nt][q] + bv;
            }
        }
    }

    if (NDOT > 0) {                                        // fused per-node dots from LDS x
        int row = tid >> 2;        // 0..63
        int kq  = tid & 3;         // 32-value k quarter
        int gr  = r0 + row;
        float xv[32];
        #pragma unroll
        for (int j = 0; j < 4; ++j) {
            int bc = kq * 64 + j * 16;
            uint4 u = *(const uint4*)((const char*)xs + row * 256 + (bc ^ ((row & 7) << 4)));
            xv[j*8+0] = b2f(u.x & 0xffffu); xv[j*8+1] = b2f(u.x >> 16);
            xv[j*8+2] = b2f(u.y & 0xffffu); xv[j*8+3] = b2f(u.y >> 16);
            xv[j*8+4] = b2f(u.z & 0xffffu); xv[j*8+5] = b2f(u.z >> 16);
            xv[j*8+6] = b2f(u.w & 0xffffu); xv[j*8+7] = b2f(u.w >> 16);
        }
        int vi[4] = { vidx.x, vidx.y, vidx.z, vidx.w };
        float dots[NDOT > 0 ? NDOT : 1];
        #pragma unroll
        for (int v = 0; v < NDOT; ++v) {
            const float* a = av + vi[v] * 128 + kq * 32;
            float d = 0.f;
            #pragma unroll
            for (int k = 0; k < 32; ++k) d += xv[k] * a[k];
            d += __shfl_xor(d, 1);
            d += __shfl_xor(d, 2);
            dots[v] = d;
        }
        if (kq == 0 && gr < N) {
            if (NDOT == 4) {
                *(float2*)(oes + 2 * gr) = make_float2(dots[0], dots[1]);
                oda[gr] = dots[2];
                odb[gr] = dots[3];
            } else if (NDOT == 2) {
                oes[gr] = dots[0];
                oda[gr] = dots[1];
            }
        }
    }
}

// ---------------------------------------------------------------- CSR build
__global__ void hist_edges(const int* __restrict__ gg_d, const int* __restrict__ gd_d,
                           const int* __restrict__ dg_d, int* __restrict__ counts)
{
    int i = blockIdx.x * blockDim.x + threadIdx.x;
    if (i >= ETOT) return;
    int slot;
    if (i < EGG) slot = gg_d[i];
    else if (i < EGG + EGD) slot = NGENE + gd_d[i - EGG];
    else slot = NGENE + NDIS + dg_d[i - EGG - EGD];
    atomicAdd(&counts[slot], 1);
}

__global__ __launch_bounds__(256) void scan_blocks(const int* __restrict__ counts, int* __restrict__ rowptr,
                                                   int* __restrict__ partials, int n)
{
    __shared__ int sdata[256];
    int base = blockIdx.x * 2048;
    int tid  = threadIdx.x;
    int local[8]; int s = 0;
    #pragma unroll
    for (int j = 0; j < 8; ++j) {
        int idx = base + tid * 8 + j;
        int v = (idx < n) ? counts[idx] : 0;
        local[j] = s; s += v;
    }
    sdata[tid] = s;
    __syncthreads();
    for (int off = 1; off < 256; off <<= 1) {
        int v = 0;
        if (tid >= off) v = sdata[tid - off];
        __syncthreads();
        if (tid >= off) sdata[tid] += v;
        __syncthreads();
    }
    int texcl = (tid ? sdata[tid - 1] : 0);
    #pragma unroll
    for (int j = 0; j < 8; ++j) {
        int idx = base + tid * 8 + j;
        if (idx < n) rowptr[idx] = local[j] + texcl;
    }
    if (tid == 255) partials[blockIdx.x] = sdata[255];
}

__global__ __launch_bounds__(256) void scan_partials(int* __restrict__ partials, int nb)
{
    __shared__ int sdata[256];
    int tid = threadIdx.x;
    sdata[tid] = (tid < nb) ? partials[tid] : 0;
    __syncthreads();
    for (int off = 1; off < 256; off <<= 1) {
        int v = 0;
        if (tid >= off) v = sdata[tid - off];
        __syncthreads();
        if (tid >= off) sdata[tid] += v;
        __syncthreads();
    }
    partials[tid] = (tid ? sdata[tid - 1] : 0);
}

__global__ void scan_add(int* __restrict__ rowptr, const int* __restrict__ partials, int n)
{
    int i = blockIdx.x * blockDim.x + threadIdx.x;
    if (i < n) rowptr[i] += partials[i >> 11];
    if (i == 0) rowptr[n] = ETOT;
}

// scatter: single 4B store per edge (unified source index encodes projection row)
__global__ void scatter_edges(const int* __restrict__ gg_s, const int* __restrict__ gg_d,
                              const int* __restrict__ gd_s, const int* __restrict__ gd_d,
                              const int* __restrict__ dg_s, const int* __restrict__ dg_d,
                              const int* __restrict__ rowptr, int* __restrict__ cursor,
                              int* __restrict__ colu)
{
    int i = blockIdx.x * blockDim.x + threadIdx.x;
    if (i >= ETOT) return;
    int slot, srcu;
    if (i < EGG) { slot = gg_d[i]; srcu = 2 * gg_s[i]; }
    else if (i < EGG + EGD) { int j = i - EGG; slot = NGENE + gd_d[j]; srcu = 2 * gd_s[j] + 1; }
    else { int j = i - EGG - EGD; slot = NGENE + NDIS + dg_d[j]; srcu = 2 * NGENE + dg_s[j]; }
    int pos = atomicAdd(&cursor[slot], 1);
    colu[rowptr[slot] + pos] = srcu;
}

// ---------------------------------------------------------------- aggregate: inline softmax, 16 lanes/node
__device__ __forceinline__ void seg_go(int slot, const int* __restrict__ rowptr,
                                       const int* __restrict__ colu, const float* __restrict__ su,
                                       const float* __restrict__ edu, const uint4* __restrict__ hsu,
                                       int gl, float acc[8])
{
    int s = rowptr[slot], e = rowptr[slot + 1];
    if (e <= s) return;
    float edv = edu[slot];
    float sx[8];
    #pragma unroll
    for (int j = 0; j < 8; ++j) sx[j] = 0.f;
    float den = 0.f;
    int c = colu[s]; float sc = su[c];
    uint4 h = hsu[(size_t)c * 16 + gl];
    for (int i = s + 1; i < e; ++i) {
        int c1 = colu[i]; float sc1 = su[c1];
        uint4 h1 = hsu[(size_t)c1 * 16 + gl];          // in flight while consuming h
        float el = sc + edv; el = el > 0.f ? el : SLOPE * el;
        float p = __expf(fminf(el, 80.f));
        den += p;
        sx[0] += p * b2f(h.x & 0xffffu); sx[1] += p * b2f(h.x >> 16);
        sx[2] += p * b2f(h.y & 0xffffu); sx[3] += p * b2f(h.y >> 16);
        sx[4] += p * b2f(h.z & 0xffffu); sx[5] += p * b2f(h.z >> 16);
        sx[6] += p * b2f(h.w & 0xffffu); sx[7] += p * b2f(h.w >> 16);
        sc = sc1; h = h1;
    }
    float el = sc + edv; el = el > 0.f ? el : SLOPE * el;
    float p = __expf(fminf(el, 80.f));
    den += p;
    sx[0] += p * b2f(h.x & 0xffffu); sx[1] += p * b2f(h.x >> 16);
    sx[2] += p * b2f(h.y & 0xffffu); sx[3] += p * b2f(h.y >> 16);
    sx[4] += p * b2f(h.z & 0xffffu); sx[5] += p * b2f(h.z >> 16);
    sx[6] += p * b2f(h.w & 0xffffu); sx[7] += p * b2f(h.w >> 16);
    float inv = 1.0f / den;
    #pragma unroll
    for (int j = 0; j < 8; ++j) acc[j] += sx[j] * inv;
}

template<bool TWO>
__global__ __launch_bounds__(256) void agg_seg(const int* __restrict__ rowptr, const int* __restrict__ colu,
                                              const float* __restrict__ su, const float* __restrict__ edu,
                                              const uint4* __restrict__ hsu,
                                              int slotA0, int slotB0,
                                              const float* __restrict__ biasA, const float* __restrict__ biasB,
                                              uint4* __restrict__ out, int N)
{
    int g  = blockIdx.x * 16 + (threadIdx.x >> 4);
    int gl = threadIdx.x & 15;
    if (g >= N) return;
    float acc[8];
    #pragma unroll
    for (int j = 0; j < 8; ++j) acc[j] = 0.f;
    seg_go(slotA0 + g, rowptr, colu, su, edu, hsu, gl, acc);
    if (TWO) seg_go(slotB0 + g, rowptr, colu, su, edu, hsu, gl, acc);

    float4 bA0 = ((const float4*)biasA)[gl * 2];
    float4 bA1 = ((const float4*)biasA)[gl * 2 + 1];
    float b0 = bA0.x, b1 = bA0.y, b2 = bA0.z, b3 = bA0.w;
    float b4 = bA1.x, b5 = bA1.y, b6 = bA1.z, b7 = bA1.w;
    if (TWO) {
        float4 bB0 = ((const float4*)biasB)[gl * 2];
        float4 bB1 = ((const float4*)biasB)[gl * 2 + 1];
        b0 += bB0.x; b1 += bB0.y; b2 += bB0.z; b3 += bB0.w;
        b4 += bB1.x; b5 += bB1.y; b6 += bB1.z; b7 += bB1.w;
    }
    uint4 o;
    o.x = pack2(fmaxf(acc[0] + b0, 0.f), fmaxf(acc[1] + b1, 0.f));
    o.y = pack2(fmaxf(acc[2] + b2, 0.f), fmaxf(acc[3] + b3, 0.f));
    o.z = pack2(fmaxf(acc[4] + b4, 0.f), fmaxf(acc[5] + b5, 0.f));
    o.w = pack2(fmaxf(acc[6] + b6, 0.f), fmaxf(acc[7] + b7, 0.f));
    out[(size_t)g * 16 + gl] = o;
}

// ---------------------------------------------------------------- launch
extern "C" void kernel_launch(void* const* d_in, const int* in_sizes, int n_in,
                              void* d_out, int out_size, void* d_ws, size_t ws_size,
                              hipStream_t stream)
{
    const float* xg  = (const float*)d_in[0];
    const float* xd  = (const float*)d_in[1];
    const float* Ws1 = (const float*)d_in[2];
    const float* Wd1 = (const float*)d_in[3];
    const float* as1 = (const float*)d_in[4];
    const float* ad1 = (const float*)d_in[5];
    const float* b1  = (const float*)d_in[6];
    const float* Ws2 = (const float*)d_in[7];
    const float* Wd2 = (const float*)d_in[8];
    const float* as2 = (const float*)d_in[9];
    const float* ad2 = (const float*)d_in[10];
    const float* b2  = (const float*)d_in[11];
    const float* Wg  = (const float*)d_in[12];
    const float* bg  = (const float*)d_in[13];
    const float* Wdh = (const float*)d_in[14];
    const float* bd  = (const float*)d_in[15];
    const int* gg_s = (const int*)d_in[16];
    const int* gg_d = (const int*)d_in[17];
    const int* gd_s = (const int*)d_in[18];
    const int* gd_d = (const int*)d_in[19];
    const int* dg_s = (const int*)d_in[20];
    const int* dg_d = (const int*)d_in[21];
    float* out = (float*)d_out;

    size_t p = 0;
    char* ws = (char*)d_ws;
    auto alloc_f = [&](size_t n) { p = (p + 255) & ~(size_t)255; float* r = (float*)(ws + p);  p += n * sizeof(float);  return r; };
    auto alloc_i = [&](size_t n) { p = (p + 255) & ~(size_t)255; int* r = (int*)(ws + p);      p += n * sizeof(int);    return r; };
    auto alloc_u = [&](size_t n) { p = (p + 255) & ~(size_t)255; ushort* r = (ushort*)(ws + p); p += n * sizeof(ushort); return r; };

    ushort* xgb  = alloc_u((size_t)NGENE * FDIM);
    ushort* xdb  = alloc_u((size_t)NDIS  * FDIM);
    ushort* hsu  = alloc_u((size_t)NSRC * HIDD);   // rows: gene t0=2n, t1=2n+1 | dis t2 = 2NG+d
    ushort* h1gb = alloc_u((size_t)NGENE * HIDD);
    ushort* h1db = alloc_u((size_t)NDIS  * HIDD);
    ushort* wt1  = alloc_u(3 * 128 * 128);
    ushort* wt2  = alloc_u(3 * 128 * 128);
    ushort* wtg  = alloc_u(64 * 128);
    ushort* wtd  = alloc_u(64 * 128);
    float* av   = alloc_f(12 * 128);
    float* esu  = alloc_f(NSRC);        // matches srcu indexing
    float* edu  = alloc_f(NSLOT);       // matches slot indexing
    int* counts   = alloc_i(NSLOT);
    int* rowptr   = alloc_i(NSLOT + 1);
    int* partials = alloc_i(256);
    int* colu     = alloc_i(ETOT);
    (void)ws_size; (void)in_sizes; (void)n_in; (void)out_size;

    const int SCAN_BLOCKS = (NSLOT + 2047) / 2048;   // 108

    ushort* hs_dis = hsu + (size_t)2 * NGENE * HIDD;
    float* es_dis = esu + 2 * NGENE;
    float* ed0 = edu;                    // gene dst of g2g
    float* ed1 = edu + NGENE;            // dis dst of g2d
    float* ed2 = edu + NGENE + NDIS;     // gene dst of d2g

    // ---- CSR build (shared by both layers)
    hipMemsetAsync(counts, 0, (size_t)NSLOT * sizeof(int), stream);
    hist_edges<<<(ETOT + 255) / 256, 256, 0, stream>>>(gg_d, gd_d, dg_d, counts);
    scan_blocks<<<SCAN_BLOCKS, 256, 0, stream>>>(counts, rowptr, partials, NSLOT);
    scan_partials<<<1, 256, 0, stream>>>(partials, SCAN_BLOCKS);
    scan_add<<<(NSLOT + 255) / 256, 256, 0, stream>>>(rowptr, partials, NSLOT);
    hipMemsetAsync(counts, 0, (size_t)NSLOT * sizeof(int), stream);
    scatter_edges<<<(ETOT + 255) / 256, 256, 0, stream>>>(gg_s, gg_d, gd_s, gd_d, dg_s, dg_d,
                                                          rowptr, counts, colu);

    // ---- bf16 conversions + attention vectors
    conv_f32_bf16<<<(NGENE * FDIM / 4 + 255) / 256, 256, 0, stream>>>(xg, xgb, NGENE * FDIM / 4);
    conv_f32_bf16<<<(NDIS  * FDIM / 4 + 255) / 256, 256, 0, stream>>>(xd, xdb, NDIS * FDIM / 4);
    conv_wt_all<<<448, 256, 0, stream>>>(Ws1, Ws2, Wg, Wdh, wt1, wt2, wtg, wtd);
    compute_av<<<1536, 64, 0, stream>>>(Ws1, Wd1, as1, ad1, Ws2, Wd2, as2, ad2, av);

    const int GB_G = (NGENE + 63) / 64, GB_D = (NDIS + 63) / 64;
    const int AB_G = (NGENE + 15) / 16, AB_D = (NDIS + 15) / 16;

    // ---- layer 1: fused dual projection + dots (gene), projection + dots (dis)
    gemm_mfma<256, 4, true><<<GB_G, 256, 0, stream>>>(xgb, wt1, nullptr, hsu, NGENE,
        av, make_int4(0, 1, 3, 5), esu, ed0, ed2);
    gemm_mfma<128, 2, true><<<GB_D, 256, 0, stream>>>(xdb, wt1 + 2 * 128 * 128, nullptr, hs_dis, NDIS,
        av, make_int4(2, 4, 0, 0), es_dis, ed1, nullptr);
    agg_seg<true><<<AB_G, 256, 0, stream>>>(rowptr, colu, esu, edu, (const uint4*)hsu,
        0, NGENE + NDIS, b1 + 0 * 128, b1 + 2 * 128, (uint4*)h1gb, NGENE);
    agg_seg<false><<<AB_D, 256, 0, stream>>>(rowptr, colu, esu, edu, (const uint4*)hsu,
        NGENE, 0, b1 + 1 * 128, nullptr, (uint4*)h1db, NDIS);

    // ---- layer 2
    gemm_mfma<256, 4, true><<<GB_G, 256, 0, stream>>>(h1gb, wt2, nullptr, hsu, NGENE,
        av, make_int4(6, 7, 9, 11), esu, ed0, ed2);
    gemm_mfma<128, 2, true><<<GB_D, 256, 0, stream>>>(h1db, wt2 + 2 * 128 * 128, nullptr, hs_dis, NDIS,
        av, make_int4(8, 10, 0, 0), es_dis, ed1, nullptr);
    agg_seg<true><<<AB_G, 256, 0, stream>>>(rowptr, colu, esu, edu, (const uint4*)hsu,
        0, NGENE + NDIS, b2 + 0 * 128, b2 + 2 * 128, (uint4*)h1gb, NGENE);
    agg_seg<false><<<AB_D, 256, 0, stream>>>(rowptr, colu, esu, edu, (const uint4*)hsu,
        NGENE, 0, b2 + 1 * 128, nullptr, (uint4*)h1db, NDIS);

    // ---- output heads (bf16 MFMA, fp32 out + bias, gene first)
    gemm_mfma<64, 0, false><<<GB_G, 256, 0, stream>>>(h1gb, wtg, bg, out, NGENE,
        av, make_int4(0, 0, 0, 0), nullptr, nullptr, nullptr);
    gemm_mfma<64, 0, false><<<GB_D, 256, 0, stream>>>(h1db, wtd, bd, out + (size_t)NGENE * OUTF, NDIS,
        av, make_int4(0, 0, 0, 0), nullptr, nullptr, nullptr);
}